// Round 4
// baseline (3580.816 us; speedup 1.0000x reference)
//
#include <hip/hip_runtime.h>
#include <hip/hip_bf16.h>

typedef __hip_bfloat16 bf16;
typedef unsigned int u32;

constexpr int cN0 = 400000, cN1 = 100000, cN2 = 25000;
constexpr int cNTOT = cN0 + cN1 + cN2;
constexpr int cE0 = 1600000, cE1 = 400000, cE2 = 100000;

static __device__ __forceinline__ float b2f(bf16 x) { return __bfloat162float(x); }
// Dual-path input read (flag==0: bf16 — expected; flag!=0: fp32 insurance)
static __device__ __forceinline__ float lin(const void* p, size_t i, int f32) {
    return f32 ? ((const float*)p)[i] : b2f(((const bf16*)p)[i]);
}

// ---------------- dtype detector (bf16 N(0,1) data never has exponent>=133) ----------------
__global__ void detect_kernel(const unsigned short* __restrict__ sf, int* __restrict__ flag)
{
    int t = threadIdx.x;
    int bad = 0;
#pragma unroll
    for (int q = 0; q < 16; q++) {
        unsigned short h = sf[t * 16 + q];
        int e = (h >> 7) & 0xFF;
        if (e >= 133) bad++;
    }
    if (bad) atomicAdd(flag, bad);
}
__global__ void zint_kernel(int* p, int n) { int t = blockIdx.x * 256 + threadIdx.x; if (t < n) p[t] = 0; }

// ---------------- Encoder (shfl broadcast, no LDS) ----------------
__global__ void enc_kernel(const int* __restrict__ flagp,
                           const void* __restrict__ stat, const void* __restrict__ dyn,
                           const void* __restrict__ W1, const void* __restrict__ b1,
                           const void* __restrict__ W2, const void* __restrict__ b2,
                           const void* __restrict__ pa, bf16* __restrict__ X, int nn)
{
    const int f = *flagp;
    const int lane = threadIdx.x & 63;
    const int wid  = blockIdx.x * (blockDim.x >> 6) + (threadIdx.x >> 6);
    const int nw   = gridDim.x * (blockDim.x >> 6);
    float w1r[16], w2r[64];
#pragma unroll
    for (int k = 0; k < 16; k++) w1r[k] = lin(W1, k * 64 + lane, f);
#pragma unroll
    for (int k = 0; k < 64; k++) w2r[k] = lin(W2, k * 64 + lane, f);
    const float bb1 = lin(b1, lane, f);
    const float bb2 = lin(b2, lane, f);
    const float a   = lin(pa, 0, f);
    for (int n = wid; n < nn; n += nw) {
        float t1 = bb1;
#pragma unroll
        for (int k = 0; k < 6; k++)  t1 += lin(stat, (size_t)n * 6 + k, f) * w1r[k];
#pragma unroll
        for (int k = 0; k < 10; k++) t1 += lin(dyn, (size_t)n * 10 + k, f) * w1r[6 + k];
        t1 = t1 > 0.f ? t1 : a * t1;
        float t2 = bb2;
#pragma unroll
        for (int k = 0; k < 64; k++) t2 += __shfl(t1, k) * w2r[k];
        t2 = t2 > 0.f ? t2 : a * t2;
        X[(size_t)n * 64 + lane] = __float2bfloat16(t2);
    }
}

// ---------------- degree / CSR build ----------------
__global__ void fill1_kernel(float* p, int n) { int t = blockIdx.x * 256 + threadIdx.x; if (t < n) p[t] = 1.f; }
__global__ void degacc_kernel(const int* __restrict__ flagp, const int* __restrict__ dst,
                              const void* __restrict__ ew, float* __restrict__ deg, int ne)
{
    const int f = *flagp;
    int e = blockIdx.x * 256 + threadIdx.x;
    if (e < ne) unsafeAtomicAdd(&deg[dst[e]], lin(ew, e, f));
}
__global__ void rsqrt_kernel(float* p, int n) { int t = blockIdx.x * 256 + threadIdx.x; if (t < n) p[t] = rsqrtf(p[t]); }
__global__ void cnt_edge_kernel(const int* __restrict__ dst, int* __restrict__ cnt, int ne)
{
    int e = blockIdx.x * 256 + threadIdx.x;
    if (e < ne) atomicAdd(&cnt[dst[e]], 1);
}
__global__ void grab_kernel(const int* __restrict__ cnt, int* __restrict__ base,
                            int* __restrict__ cur, int* __restrict__ gc, int n)
{
    int t = blockIdx.x * 256 + threadIdx.x;
    if (t < n) { int b = atomicAdd(gc, cnt[t]); base[t] = b; cur[t] = b; }
}
__global__ void fill_edge_kernel(const int* __restrict__ flagp, const int* __restrict__ src,
                                 const int* __restrict__ dst, const void* __restrict__ ew,
                                 const float* __restrict__ dinv, int* __restrict__ cur,
                                 int* __restrict__ srcp, bf16* __restrict__ normp, int ne)
{
    const int f = *flagp;
    int e = blockIdx.x * 256 + threadIdx.x;
    if (e >= ne) return;
    int d = dst[e], s = src[e];
    int pos = atomicAdd(&cur[d], 1);
    srcp[pos]  = s;
    normp[pos] = __float2bfloat16(dinv[s] * lin(ew, e, f) * dinv[d]);
}
__global__ void cnt_idx_kernel(const int* __restrict__ idx, int* __restrict__ cnt, int n)
{
    int j = blockIdx.x * 256 + threadIdx.x;
    if (j < n) atomicAdd(&cnt[idx[j]], 1);
}
__global__ void fill_idx_kernel(const int* __restrict__ idx, int* __restrict__ cur,
                                int* __restrict__ jp, int n)
{
    int j = blockIdx.x * 256 + threadIdx.x;
    if (j >= n) return;
    int pos = atomicAdd(&cur[idx[j]], 1);
    jp[pos] = j;
}

// ---------------- Fused conv: gather -> shfl-GEMM -> tanh -> direct filter acc ----------------
__global__ void fused_conv_kernel(const int* __restrict__ flagp,
                                  const int* __restrict__ base, const int* __restrict__ cnt,
                                  const int* __restrict__ srcp, const bf16* __restrict__ normp,
                                  const bf16* __restrict__ h_in, bf16* __restrict__ h_out,
                                  const float* __restrict__ dinv,
                                  const void* __restrict__ W, int woff,
                                  const void* __restrict__ bias, int boff,
                                  const void* __restrict__ filt, int foff, int first,
                                  float* __restrict__ acc, int nn)
{
    const int f = *flagp;
    const int lane = threadIdx.x & 63;
    const int wid  = blockIdx.x * (blockDim.x >> 6) + (threadIdx.x >> 6);
    const int nw   = gridDim.x * (blockDim.x >> 6);
    float wr[64];
#pragma unroll
    for (int k = 0; k < 64; k++) wr[k] = lin(W, (size_t)woff + k * 64 + lane, f);
    const float bb = lin(bias, (size_t)boff + lane, f);
    const float fc = lin(filt, foff, f);
    for (int n = wid; n < nn; n += nw) {
        const int bs = base[n], c = cnt[n];
        float g = 0.f;
        for (int j = bs; j < bs + c; j++) {
            int sn = srcp[j];
            float nm = b2f(normp[j]);
            g += nm * b2f(h_in[(size_t)sn * 64 + lane]);
        }
        const float di = dinv[n];
        g += b2f(h_in[(size_t)n * 64 + lane]) * di * di;
        float s = bb;
#pragma unroll
        for (int k = 0; k < 64; k++) s += __shfl(g, k) * wr[k];
        const float h = tanhf(s);
        const size_t ai = (size_t)n * 64 + lane;
        h_out[ai] = __float2bfloat16(h);
        acc[ai] = (first ? 0.f : acc[ai]) + fc * h;
    }
}

// ---------------- pooling gather ----------------
__global__ void pool_gather_kernel(const int* __restrict__ base, const int* __restrict__ cnt,
                                   const int* __restrict__ jp, const float* __restrict__ accc,
                                   float* __restrict__ fin, int nn)
{
    const int lane = threadIdx.x & 63;
    const int n = blockIdx.x * (blockDim.x >> 6) + (threadIdx.x >> 6);
    if (n >= nn) return;
    const int m = cnt[n];
    if (m == 0) return;
    const int bs = base[n];
    float s = 0.f;
    for (int t = bs; t < bs + m; t++) {
        int j = jp[t];
        s += accc[(size_t)j * 64 + lane];
    }
    fin[(size_t)n * 64 + lane] += s / (float)m;
}

// ---------------- Decoder (fp32 output!) ----------------
__global__ void dec_kernel(const int* __restrict__ flagp, const float* __restrict__ fin,
                           const void* __restrict__ W1, const void* __restrict__ b1,
                           const void* __restrict__ W2, const void* __restrict__ b2,
                           const void* __restrict__ pa, float* __restrict__ out, int nn)
{
    const int f = *flagp;
    const int lane = threadIdx.x & 63;
    const int wid  = blockIdx.x * (blockDim.x >> 6) + (threadIdx.x >> 6);
    const int nw   = gridDim.x * (blockDim.x >> 6);
    float w1r[64];
#pragma unroll
    for (int k = 0; k < 64; k++) w1r[k] = lin(W1, k * 64 + lane, f);
    const float bb1 = lin(b1, lane, f);
    const float w20 = lin(W2, lane * 2 + 0, f);
    const float w21 = lin(W2, lane * 2 + 1, f);
    const float bb20 = lin(b2, 0, f);
    const float bb21 = lin(b2, 1, f);
    const float a = lin(pa, 0, f);
    for (int n = wid; n < nn; n += nw) {
        const float4* fr = (const float4*)(fin + (size_t)n * 64);
        float y = bb1;
#pragma unroll
        for (int q = 0; q < 16; q++) {
            float4 v = fr[q];
            y += v.x * w1r[4*q] + v.y * w1r[4*q+1] + v.z * w1r[4*q+2] + v.w * w1r[4*q+3];
        }
        y = y > 0.f ? y : a * y;
        float p0 = y * w20, p1 = y * w21;
#pragma unroll
        for (int m = 32; m; m >>= 1) { p0 += __shfl_xor(p0, m); p1 += __shfl_xor(p1, m); }
        if (lane == 0) {
            float o0 = p0 + bb20; o0 = o0 > 0.f ? o0 : a * o0;
            float o1 = p1 + bb21; o1 = o1 > 0.f ? o1 : a * o1;
            ((float2*)out)[n] = make_float2(o0, o1);
        }
    }
}

extern "C" void kernel_launch(void* const* d_in, const int* in_sizes, int n_in,
                              void* d_out, int out_size, void* d_ws, size_t ws_size,
                              hipStream_t stream)
{
    const void* stat = d_in[0];
    const void* dyn  = d_in[1];
    const int*  ei[3]   = {(const int*)d_in[2], (const int*)d_in[4], (const int*)d_in[6]};
    const void* ea[3]   = {d_in[3], d_in[5], d_in[7]};
    const int*  pidx[2] = {(const int*)d_in[8], (const int*)d_in[9]};
    const void* encW1 = d_in[10]; const void* encb1 = d_in[11];
    const void* encW2 = d_in[12]; const void* encb2 = d_in[13];
    const void* encpa = d_in[14];
    const void* gW    = d_in[15]; const void* gbias = d_in[16];
    const void* filt  = d_in[17];
    const void* dW1   = d_in[18]; const void* db1   = d_in[19];
    const void* dW2   = d_in[20]; const void* db2   = d_in[21];
    const void* dpa   = d_in[22];

    auto al = [](size_t x) { return (x + 255) & ~(size_t)255; };
    char* w = (char*)d_ws;
    size_t off = 0;
    bf16* X    = (bf16*)(w + off); off += al((size_t)cNTOT * 64 * 2);   // 67.2 MB
    bf16* HB   = (bf16*)(w + off); off += al((size_t)cN0 * 64 * 2);     // 51.2 MB
    float* FIN = (float*)(w + off); off += al((size_t)cN0 * 64 * 4);    // 102.4 MB
    float* ACCC= (float*)(w + off); off += al((size_t)cN1 * 64 * 4);    // 25.6 MB
    float* DINV= (float*)(w + off); off += al((size_t)cN0 * 4);
    int* CNTI  = (int*)(w + off);  off += al((size_t)cN0 * 4);
    int* BASE  = (int*)(w + off);  off += al((size_t)cN0 * 4);
    int* CUR   = (int*)(w + off);  off += al((size_t)cN0 * 4);
    int* SRCP  = (int*)(w + off);  off += al((size_t)cE0 * 4);
    bf16* NORMP= (bf16*)(w + off); off += al((size_t)cE0 * 2);
    int* JP    = (int*)(w + off);  off += al((size_t)cN1 * 4);
    int* FLAG  = (int*)(w + off);  off += 256;
    int* GC    = (int*)(w + off);  off += 256;   // total ~263 MB (fits: round 3 ran without fault)

    const int Ns[3]  = {cN0, cN1, cN2};
    const int Es[3]  = {cE0, cE1, cE2};
    const int ptr[3] = {0, cN0, cN0 + cN1};
#define NB(x) (((x) + 255) / 256)

    zint_kernel<<<1, 256, 0, stream>>>(FLAG, 1);
    detect_kernel<<<1, 256, 0, stream>>>((const unsigned short*)stat, FLAG);

    enc_kernel<<<2048, 256, 0, stream>>>(FLAG, stat, dyn, encW1, encb1, encW2, encb2, encpa, X, cNTOT);

    for (int i = 0; i < 3; i++) {
        const int* srcp_in = ei[i];
        const int* dstp    = ei[i] + Es[i];
        fill1_kernel <<<NB(Ns[i]), 256, 0, stream>>>(DINV, Ns[i]);
        degacc_kernel<<<NB(Es[i]), 256, 0, stream>>>(FLAG, dstp, ea[i], DINV, Es[i]);
        rsqrt_kernel <<<NB(Ns[i]), 256, 0, stream>>>(DINV, Ns[i]);
        zint_kernel    <<<NB(Ns[i]), 256, 0, stream>>>(CNTI, Ns[i]);
        zint_kernel    <<<1, 256, 0, stream>>>(GC, 1);
        cnt_edge_kernel<<<NB(Es[i]), 256, 0, stream>>>(dstp, CNTI, Es[i]);
        grab_kernel    <<<NB(Ns[i]), 256, 0, stream>>>(CNTI, BASE, CUR, GC, Ns[i]);
        fill_edge_kernel<<<NB(Es[i]), 256, 0, stream>>>(FLAG, srcp_in, dstp, ea[i], DINV, CUR, SRCP, NORMP, Es[i]);

        bf16* ping = X + (size_t)ptr[i] * 64;
        bf16* pong = HB;
        float* acc_i = (i == 0) ? FIN : ACCC;
        for (int k = 0; k < 3; k++) {
            bf16* hin  = (k & 1) ? pong : ping;
            bf16* hout = (k & 1) ? ping : pong;
            fused_conv_kernel<<<2048, 256, 0, stream>>>(FLAG, BASE, CNTI, SRCP, NORMP,
                hin, hout, DINV, gW, i * 4096, gbias, i * 64,
                filt, i * 3 + k, (k == 0) ? 1 : 0, acc_i, Ns[i]);
        }
        if (i >= 1) {
            int nj = (i == 1) ? cN1 : cN2;
            const int* pp = pidx[i - 1];
            zint_kernel    <<<NB(cN0), 256, 0, stream>>>(CNTI, cN0);
            zint_kernel    <<<1, 256, 0, stream>>>(GC, 1);
            cnt_idx_kernel <<<NB(nj), 256, 0, stream>>>(pp, CNTI, nj);
            grab_kernel    <<<NB(cN0), 256, 0, stream>>>(CNTI, BASE, CUR, GC, cN0);
            fill_idx_kernel<<<NB(nj), 256, 0, stream>>>(pp, CUR, JP, nj);
            pool_gather_kernel<<<(cN0 + 3) / 4, 256, 0, stream>>>(BASE, CNTI, JP, ACCC, FIN, cN0);
        }
    }
    dec_kernel<<<2048, 256, 0, stream>>>(FLAG, FIN, dW1, db1, dW2, db2, dpa, (float*)d_out, cN0);
#undef NB
}

// Round 7
// 2919.128 us; speedup vs baseline: 1.2267x; 1.2267x over previous
//
#include <hip/hip_runtime.h>
#include <hip/hip_bf16.h>

typedef __hip_bfloat16 bf16;

// Inputs are fp32 (established empirically: every raw-bf16-read run NaN'd via
// fp32-mantissa->bf16-NaN garbage; the R3/R4 runtime detector always took the
// fp32 path and passed). Output is fp32 (R4 passed with fp32 float2 stores).
constexpr int cN0 = 400000, cN1 = 100000, cN2 = 25000;
constexpr int cNTOT = cN0 + cN1 + cN2;
constexpr int cE0 = 1600000, cE1 = 400000, cE2 = 100000;

static __device__ __forceinline__ float b2f(bf16 x) { return __bfloat162float(x); }

// ---------------- Encoder ----------------
__global__ void enc_kernel(const float* __restrict__ stat, const float* __restrict__ dyn,
                           const float* __restrict__ W1, const float* __restrict__ b1,
                           const float* __restrict__ W2, const float* __restrict__ b2,
                           const float* __restrict__ pa, bf16* __restrict__ X, int nn)
{
    const int lane = threadIdx.x & 63;
    const int wid  = blockIdx.x * (blockDim.x >> 6) + (threadIdx.x >> 6);
    const int nw   = gridDim.x * (blockDim.x >> 6);
    float w1r[16], w2r[64];
#pragma unroll
    for (int k = 0; k < 16; k++) w1r[k] = W1[k * 64 + lane];
#pragma unroll
    for (int k = 0; k < 64; k++) w2r[k] = W2[k * 64 + lane];
    const float bb1 = b1[lane];
    const float bb2 = b2[lane];
    const float a   = pa[0];
    for (int n = wid; n < nn; n += nw) {
        float t1 = bb1;
#pragma unroll
        for (int k = 0; k < 6; k++)  t1 += stat[(size_t)n * 6 + k] * w1r[k];
#pragma unroll
        for (int k = 0; k < 10; k++) t1 += dyn[(size_t)n * 10 + k] * w1r[6 + k];
        t1 = t1 > 0.f ? t1 : a * t1;
        float t2 = bb2;
#pragma unroll
        for (int k = 0; k < 64; k++) t2 += __shfl(t1, k) * w2r[k];
        t2 = t2 > 0.f ? t2 : a * t2;
        X[(size_t)n * 64 + lane] = __float2bfloat16(t2);
    }
}

// ---------------- degree / CSR build (R4-proven separate passes) ----------------
__global__ void zint_kernel(int* p, int n)   { int t = blockIdx.x * 256 + threadIdx.x; if (t < n) p[t] = 0; }
__global__ void fill1_kernel(float* p, int n){ int t = blockIdx.x * 256 + threadIdx.x; if (t < n) p[t] = 1.f; }
__global__ void degacc_kernel(const int* __restrict__ dst, const float* __restrict__ ew,
                              float* __restrict__ deg, int ne)
{
    int e = blockIdx.x * 256 + threadIdx.x;
    if (e < ne) unsafeAtomicAdd(&deg[dst[e]], ew[e]);
}
__global__ void rsqrt_kernel(float* p, int n){ int t = blockIdx.x * 256 + threadIdx.x; if (t < n) p[t] = rsqrtf(p[t]); }
__global__ void cnt_edge_kernel(const int* __restrict__ dst, int* __restrict__ cnt, int ne)
{
    int e = blockIdx.x * 256 + threadIdx.x;
    if (e < ne) atomicAdd(&cnt[dst[e]], 1);
}
__global__ void grab_kernel(const int* __restrict__ cnt, int* __restrict__ base,
                            int* __restrict__ cur, int* __restrict__ gc, int n)
{
    int t = blockIdx.x * 256 + threadIdx.x;
    if (t < n) { int b = atomicAdd(gc, cnt[t]); base[t] = b; cur[t] = b; }
}
__global__ void fill_edge_kernel(const int* __restrict__ src, const int* __restrict__ dst,
                                 const float* __restrict__ ew, const float* __restrict__ dinv,
                                 int* __restrict__ cur, int* __restrict__ srcp,
                                 bf16* __restrict__ normp, int ne)
{
    int e = blockIdx.x * 256 + threadIdx.x;
    if (e >= ne) return;
    int d = dst[e], s = src[e];
    int pos = atomicAdd(&cur[d], 1);
    srcp[pos]  = s;
    normp[pos] = __float2bfloat16(dinv[s] * ew[e] * dinv[d]);
}
__global__ void cnt_idx_kernel(const int* __restrict__ idx, int* __restrict__ cnt, int n)
{
    int j = blockIdx.x * 256 + threadIdx.x;
    if (j < n) atomicAdd(&cnt[idx[j]], 1);
}
__global__ void fill_idx_kernel(const int* __restrict__ idx, int* __restrict__ cur,
                                int* __restrict__ jp, int n)
{
    int j = blockIdx.x * 256 + threadIdx.x;
    if (j >= n) return;
    int pos = atomicAdd(&cur[idx[j]], 1);
    jp[pos] = j;
}

// ---- Fused conv: batched-ILP gather -> shfl-GEMM -> tanh -> filter acc -------------------
// Reads h_in (neighbors + self), writes h_out (must NOT alias h_in) and acc.
__global__ void fused_conv_kernel(const int* __restrict__ base, const int* __restrict__ cnt,
                                  const int* __restrict__ srcp, const bf16* __restrict__ normp,
                                  const bf16* __restrict__ h_in, bf16* __restrict__ h_out,
                                  const float* __restrict__ dinv,
                                  const float* __restrict__ W, int woff,
                                  const float* __restrict__ bias, int boff,
                                  const float* __restrict__ filt, int foff,
                                  int first, int store_h, float* __restrict__ acc, int nn)
{
    const int lane = threadIdx.x & 63;
    const int wid  = blockIdx.x * (blockDim.x >> 6) + (threadIdx.x >> 6);
    const int nw   = gridDim.x * (blockDim.x >> 6);
    float wr[64];
#pragma unroll
    for (int k = 0; k < 64; k++) wr[k] = W[(size_t)woff + k * 64 + lane];
    const float bb = bias[boff + lane];
    const float fc = filt[foff];
    for (int n = wid; n < nn; n += nw) {
        const int bs = base[n], c = cnt[n];
        const float di = dinv[n];
        float g = b2f(h_in[(size_t)n * 64 + lane]) * di * di;   // self-loop term
        for (int ch = 0; ch < c; ch += 64) {
            const int cc = min(64, c - ch);
            int sv = 0; float nv = 0.f;
            if (lane < cc) {                        // one coalesced batch load of (src, norm)
                sv = srcp[bs + ch + lane];
                nv = b2f(normp[bs + ch + lane]);
            }
            int j = 0;
            for (; j + 4 <= cc; j += 4) {           // 4 independent row gathers in flight
                int   s0 = __shfl(sv, j),     s1 = __shfl(sv, j + 1);
                int   s2 = __shfl(sv, j + 2), s3 = __shfl(sv, j + 3);
                float m0 = __shfl(nv, j),     m1 = __shfl(nv, j + 1);
                float m2 = __shfl(nv, j + 2), m3 = __shfl(nv, j + 3);
                float p0 = b2f(h_in[(size_t)s0 * 64 + lane]);
                float p1 = b2f(h_in[(size_t)s1 * 64 + lane]);
                float p2 = b2f(h_in[(size_t)s2 * 64 + lane]);
                float p3 = b2f(h_in[(size_t)s3 * 64 + lane]);
                g += m0 * p0 + m1 * p1 + m2 * p2 + m3 * p3;
            }
            for (; j < cc; j++) {
                int s0 = __shfl(sv, j);
                float m0 = __shfl(nv, j);
                g += m0 * b2f(h_in[(size_t)s0 * 64 + lane]);
            }
        }
        // in-register GEMM: s = bias + sum_k g_k * W[k][lane]
        float s = bb;
#pragma unroll
        for (int k = 0; k < 64; k++) s += __shfl(g, k) * wr[k];
        const float h = tanhf(s);
        const size_t ai = (size_t)n * 64 + lane;
        if (store_h) h_out[ai] = __float2bfloat16(h);
        acc[ai] = (first ? 0.f : acc[ai]) + fc * h;
    }
}

// ---------------- pooling gather (R4-proven serial) ----------------
__global__ void pool_gather_kernel(const int* __restrict__ base, const int* __restrict__ cnt,
                                   const int* __restrict__ jp, const float* __restrict__ accc,
                                   float* __restrict__ fin, int nn)
{
    const int lane = threadIdx.x & 63;
    const int n = blockIdx.x * (blockDim.x >> 6) + (threadIdx.x >> 6);
    if (n >= nn) return;
    const int m = cnt[n];
    if (m == 0) return;
    const int bs = base[n];
    float s = 0.f;
    for (int t = bs; t < bs + m; t++) {
        int j = jp[t];
        s += accc[(size_t)j * 64 + lane];
    }
    fin[(size_t)n * 64 + lane] += s / (float)m;
}

// ---------------- Decoder (fp32 out) ----------------
__global__ void dec_kernel(const float* __restrict__ fin,
                           const float* __restrict__ W1, const float* __restrict__ b1,
                           const float* __restrict__ W2, const float* __restrict__ b2,
                           const float* __restrict__ pa, float* __restrict__ out, int nn)
{
    const int lane = threadIdx.x & 63;
    const int wid  = blockIdx.x * (blockDim.x >> 6) + (threadIdx.x >> 6);
    const int nw   = gridDim.x * (blockDim.x >> 6);
    float w1r[64];
#pragma unroll
    for (int k = 0; k < 64; k++) w1r[k] = W1[k * 64 + lane];
    const float bb1 = b1[lane];
    const float w20 = W2[lane * 2 + 0];
    const float w21 = W2[lane * 2 + 1];
    const float bb20 = b2[0];
    const float bb21 = b2[1];
    const float a = pa[0];
    for (int n = wid; n < nn; n += nw) {
        const float4* fr = (const float4*)(fin + (size_t)n * 64);
        float y = bb1;
#pragma unroll
        for (int q = 0; q < 16; q++) {
            float4 v = fr[q];
            y += v.x * w1r[4*q] + v.y * w1r[4*q+1] + v.z * w1r[4*q+2] + v.w * w1r[4*q+3];
        }
        y = y > 0.f ? y : a * y;
        float p0 = y * w20, p1 = y * w21;
#pragma unroll
        for (int m = 32; m; m >>= 1) { p0 += __shfl_xor(p0, m); p1 += __shfl_xor(p1, m); }
        if (lane == 0) {
            float o0 = p0 + bb20; o0 = o0 > 0.f ? o0 : a * o0;
            float o1 = p1 + bb21; o1 = o1 > 0.f ? o1 : a * o1;
            ((float2*)out)[n] = make_float2(o0, o1);
        }
    }
}

extern "C" void kernel_launch(void* const* d_in, const int* in_sizes, int n_in,
                              void* d_out, int out_size, void* d_ws, size_t ws_size,
                              hipStream_t stream)
{
    const float* stat = (const float*)d_in[0];
    const float* dyn  = (const float*)d_in[1];
    const int*   ei[3]   = {(const int*)d_in[2], (const int*)d_in[4], (const int*)d_in[6]};
    const float* ea[3]   = {(const float*)d_in[3], (const float*)d_in[5], (const float*)d_in[7]};
    const int*   pidx[2] = {(const int*)d_in[8], (const int*)d_in[9]};
    const float* encW1 = (const float*)d_in[10]; const float* encb1 = (const float*)d_in[11];
    const float* encW2 = (const float*)d_in[12]; const float* encb2 = (const float*)d_in[13];
    const float* encpa = (const float*)d_in[14];
    const float* gW    = (const float*)d_in[15]; const float* gbias = (const float*)d_in[16];
    const float* filt  = (const float*)d_in[17];
    const float* dW1   = (const float*)d_in[18]; const float* db1   = (const float*)d_in[19];
    const float* dW2   = (const float*)d_in[20]; const float* db2   = (const float*)d_in[21];
    const float* dpa   = (const float*)d_in[22];

    auto al = [](size_t x) { return (x + 255) & ~(size_t)255; };
    char* w = (char*)d_ws;
    size_t off = 0;
    bf16* X    = (bf16*)(w + off); off += al((size_t)cNTOT * 64 * 2);   // 67.2 MB (h ping)
    bf16* HB   = (bf16*)(w + off); off += al((size_t)cN0 * 64 * 2);     // 51.2 MB (h pong)
    float* FIN = (float*)(w + off); off += al((size_t)cN0 * 64 * 4);    // 102.4 MB
    float* ACCC= (float*)(w + off); off += al((size_t)cN1 * 64 * 4);    // 25.6 MB
    float* DINV= (float*)(w + off); off += al((size_t)cN0 * 4);
    int* CNTI  = (int*)(w + off);  off += al((size_t)cN0 * 4);
    int* BASE  = (int*)(w + off);  off += al((size_t)cN0 * 4);
    int* CUR   = (int*)(w + off);  off += al((size_t)cN0 * 4);
    int* SRCP  = (int*)(w + off);  off += al((size_t)cE0 * 4);
    bf16* NORMP= (bf16*)(w + off); off += al((size_t)cE0 * 2);
    int* JP    = (int*)(w + off);  off += al((size_t)cN1 * 4);
    int* GC    = (int*)(w + off);  off += 256;   // ~263 MB total (proven fit, R3/R4)

    const int Ns[3]  = {cN0, cN1, cN2};
    const int Es[3]  = {cE0, cE1, cE2};
    const int ptr[3] = {0, cN0, cN0 + cN1};
#define NB(x) (((x) + 255) / 256)

    enc_kernel<<<2048, 256, 0, stream>>>(stat, dyn, encW1, encb1, encW2, encb2, encpa, X, cNTOT);

    for (int i = 0; i < 3; i++) {
        const int* srcp_in = ei[i];
        const int* dstp    = ei[i] + Es[i];
        fill1_kernel <<<NB(Ns[i]), 256, 0, stream>>>(DINV, Ns[i]);
        degacc_kernel<<<NB(Es[i]), 256, 0, stream>>>(dstp, ea[i], DINV, Es[i]);
        rsqrt_kernel <<<NB(Ns[i]), 256, 0, stream>>>(DINV, Ns[i]);
        zint_kernel    <<<NB(Ns[i]), 256, 0, stream>>>(CNTI, Ns[i]);
        zint_kernel    <<<1, 256, 0, stream>>>(GC, 1);
        cnt_edge_kernel<<<NB(Es[i]), 256, 0, stream>>>(dstp, CNTI, Es[i]);
        grab_kernel    <<<NB(Ns[i]), 256, 0, stream>>>(CNTI, BASE, CUR, GC, Ns[i]);
        fill_edge_kernel<<<NB(Es[i]), 256, 0, stream>>>(srcp_in, dstp, ea[i], DINV, CUR, SRCP, NORMP, Es[i]);

        bf16* ping = X + (size_t)ptr[i] * 64;
        bf16* pong = HB;
        float* acc_i = (i == 0) ? FIN : ACCC;
        for (int k = 0; k < 3; k++) {
            bf16* hin  = (k & 1) ? pong : ping;
            bf16* hout = (k & 1) ? ping : pong;
            fused_conv_kernel<<<2048, 256, 0, stream>>>(BASE, CNTI, SRCP, NORMP,
                hin, hout, DINV, gW, i * 4096, gbias, i * 64,
                filt, i * 3 + k, (k == 0) ? 1 : 0, (k < 2) ? 1 : 0, acc_i, Ns[i]);
        }
        if (i >= 1) {
            int nj = (i == 1) ? cN1 : cN2;
            const int* pp = pidx[i - 1];
            zint_kernel    <<<NB(cN0), 256, 0, stream>>>(CNTI, cN0);
            zint_kernel    <<<1, 256, 0, stream>>>(GC, 1);
            cnt_idx_kernel <<<NB(nj), 256, 0, stream>>>(pp, CNTI, nj);
            grab_kernel    <<<NB(cN0), 256, 0, stream>>>(CNTI, BASE, CUR, GC, cN0);
            fill_idx_kernel<<<NB(nj), 256, 0, stream>>>(pp, CUR, JP, nj);
            pool_gather_kernel<<<(cN0 + 3) / 4, 256, 0, stream>>>(BASE, CNTI, JP, ACCC, FIN, cN0);
        }
    }
    dec_kernel<<<2048, 256, 0, stream>>>(FIN, dW1, db1, dW2, db2, dpa, (float*)d_out, cN0);
#undef NB
}

// Round 8
// 2285.924 us; speedup vs baseline: 1.5665x; 1.2770x over previous
//
#include <hip/hip_runtime.h>
#include <hip/hip_bf16.h>

typedef __hip_bfloat16 bf16;

// Inputs fp32, output fp32 (established R4/R7). Intermediates bf16, accumulators fp32.
constexpr int cN0 = 400000, cN1 = 100000, cN2 = 25000;
constexpr int cNTOT = cN0 + cN1 + cN2;
constexpr int cE0 = 1600000, cE1 = 400000, cE2 = 100000;

static __device__ __forceinline__ float b2f(bf16 x) { return __bfloat162float(x); }

// LDS-broadcast 64-wide GEMM: lane-value g -> s = bias + sum_k g_k * wr[k]
// Per-wave slot; same-wave DS ordering guarantees write-before-read; wave_barrier
// stops compiler reordering. 1 ds_write + 16 ds_read_b128 (broadcast, conflict-free),
// 4 independent accumulators to break the FMA dependency chain.
static __device__ __forceinline__ float lds_gemm64(float* sb, int lane, float g,
                                                   const float* wr, float bias)
{
    sb[lane] = g;
    __builtin_amdgcn_wave_barrier();
    const float4* sb4 = (const float4*)sb;
    float a0 = bias, a1 = 0.f, a2 = 0.f, a3 = 0.f;
#pragma unroll
    for (int q = 0; q < 16; q += 4) {
        float4 v0 = sb4[q + 0], v1 = sb4[q + 1], v2 = sb4[q + 2], v3 = sb4[q + 3];
        a0 += v0.x * wr[4*q + 0]  + v0.y * wr[4*q + 1]  + v0.z * wr[4*q + 2]  + v0.w * wr[4*q + 3];
        a1 += v1.x * wr[4*q + 4]  + v1.y * wr[4*q + 5]  + v1.z * wr[4*q + 6]  + v1.w * wr[4*q + 7];
        a2 += v2.x * wr[4*q + 8]  + v2.y * wr[4*q + 9]  + v2.z * wr[4*q + 10] + v2.w * wr[4*q + 11];
        a3 += v3.x * wr[4*q + 12] + v3.y * wr[4*q + 13] + v3.z * wr[4*q + 14] + v3.w * wr[4*q + 15];
    }
    __builtin_amdgcn_wave_barrier();   // keep next iteration's write after these reads
    return (a0 + a1) + (a2 + a3);
}

// ---------------- Encoder ----------------
__global__ void enc_kernel(const float* __restrict__ stat, const float* __restrict__ dyn,
                           const float* __restrict__ W1, const float* __restrict__ b1,
                           const float* __restrict__ W2, const float* __restrict__ b2,
                           const float* __restrict__ pa, bf16* __restrict__ X, int nn)
{
    __shared__ float sb[4][64];
    const int lane = threadIdx.x & 63;
    const int slot = threadIdx.x >> 6;
    const int wid  = blockIdx.x * (blockDim.x >> 6) + slot;
    const int nw   = gridDim.x * (blockDim.x >> 6);
    float w1r[16], w2r[64];
#pragma unroll
    for (int k = 0; k < 16; k++) w1r[k] = W1[k * 64 + lane];
#pragma unroll
    for (int k = 0; k < 64; k++) w2r[k] = W2[k * 64 + lane];
    const float bb1 = b1[lane];
    const float bb2 = b2[lane];
    const float a   = pa[0];
    for (int n = wid; n < nn; n += nw) {
        float t1a = bb1, t1b = 0.f;
#pragma unroll
        for (int k = 0; k < 6; k += 2) {
            t1a += stat[(size_t)n * 6 + k]     * w1r[k];
            t1b += stat[(size_t)n * 6 + k + 1] * w1r[k + 1];
        }
#pragma unroll
        for (int k = 0; k < 10; k += 2) {
            t1a += dyn[(size_t)n * 10 + k]     * w1r[6 + k];
            t1b += dyn[(size_t)n * 10 + k + 1] * w1r[7 + k];
        }
        float t1 = t1a + t1b;
        t1 = t1 > 0.f ? t1 : a * t1;
        float t2 = lds_gemm64(sb[slot], lane, t1, w2r, bb2);
        t2 = t2 > 0.f ? t2 : a * t2;
        X[(size_t)n * 64 + lane] = __float2bfloat16(t2);
    }
}

// ---------------- degree / CSR build (R7-proven, unchanged) ----------------
__global__ void zint_kernel(int* p, int n)   { int t = blockIdx.x * 256 + threadIdx.x; if (t < n) p[t] = 0; }
__global__ void fill1_kernel(float* p, int n){ int t = blockIdx.x * 256 + threadIdx.x; if (t < n) p[t] = 1.f; }
__global__ void degacc_kernel(const int* __restrict__ dst, const float* __restrict__ ew,
                              float* __restrict__ deg, int ne)
{
    int e = blockIdx.x * 256 + threadIdx.x;
    if (e < ne) unsafeAtomicAdd(&deg[dst[e]], ew[e]);
}
__global__ void rsqrt_kernel(float* p, int n){ int t = blockIdx.x * 256 + threadIdx.x; if (t < n) p[t] = rsqrtf(p[t]); }
__global__ void cnt_edge_kernel(const int* __restrict__ dst, int* __restrict__ cnt, int ne)
{
    int e = blockIdx.x * 256 + threadIdx.x;
    if (e < ne) atomicAdd(&cnt[dst[e]], 1);
}
__global__ void grab_kernel(const int* __restrict__ cnt, int* __restrict__ base,
                            int* __restrict__ cur, int* __restrict__ gc, int n)
{
    int t = blockIdx.x * 256 + threadIdx.x;
    if (t < n) { int b = atomicAdd(gc, cnt[t]); base[t] = b; cur[t] = b; }
}
__global__ void fill_edge_kernel(const int* __restrict__ src, const int* __restrict__ dst,
                                 const float* __restrict__ ew, const float* __restrict__ dinv,
                                 int* __restrict__ cur, int* __restrict__ srcp,
                                 bf16* __restrict__ normp, int ne)
{
    int e = blockIdx.x * 256 + threadIdx.x;
    if (e >= ne) return;
    int d = dst[e], s = src[e];
    int pos = atomicAdd(&cur[d], 1);
    srcp[pos]  = s;
    normp[pos] = __float2bfloat16(dinv[s] * ew[e] * dinv[d]);
}
__global__ void cnt_idx_kernel(const int* __restrict__ idx, int* __restrict__ cnt, int n)
{
    int j = blockIdx.x * 256 + threadIdx.x;
    if (j < n) atomicAdd(&cnt[idx[j]], 1);
}
__global__ void fill_idx_kernel(const int* __restrict__ idx, int* __restrict__ cur,
                                int* __restrict__ jp, int n)
{
    int j = blockIdx.x * 256 + threadIdx.x;
    if (j >= n) return;
    int pos = atomicAdd(&cur[idx[j]], 1);
    jp[pos] = j;
}

// ---- Fused conv: batched-ILP gather -> LDS-broadcast GEMM -> tanh -> filter acc ----------
__global__ void fused_conv_kernel(const int* __restrict__ base, const int* __restrict__ cnt,
                                  const int* __restrict__ srcp, const bf16* __restrict__ normp,
                                  const bf16* __restrict__ h_in, bf16* __restrict__ h_out,
                                  const float* __restrict__ dinv,
                                  const float* __restrict__ W, int woff,
                                  const float* __restrict__ bias, int boff,
                                  const float* __restrict__ filt, int foff,
                                  int first, int store_h, float* __restrict__ acc, int nn)
{
    __shared__ float sb[4][64];
    const int lane = threadIdx.x & 63;
    const int slot = threadIdx.x >> 6;
    const int wid  = blockIdx.x * (blockDim.x >> 6) + slot;
    const int nw   = gridDim.x * (blockDim.x >> 6);
    float wr[64];
#pragma unroll
    for (int k = 0; k < 64; k++) wr[k] = W[(size_t)woff + k * 64 + lane];
    const float bb = bias[boff + lane];
    const float fc = filt[foff];
    for (int n = wid; n < nn; n += nw) {
        const int bs = base[n], c = cnt[n];
        const float di = dinv[n];
        float g = b2f(h_in[(size_t)n * 64 + lane]) * di * di;   // self-loop term
        for (int ch = 0; ch < c; ch += 64) {
            const int cc = min(64, c - ch);
            int sv = 0; float nv = 0.f;
            if (lane < cc) {                        // one coalesced batch load of (src, norm)
                sv = srcp[bs + ch + lane];
                nv = b2f(normp[bs + ch + lane]);
            }
            int j = 0;
            for (; j + 4 <= cc; j += 4) {           // 4 independent row gathers in flight
                int   s0 = __shfl(sv, j),     s1 = __shfl(sv, j + 1);
                int   s2 = __shfl(sv, j + 2), s3 = __shfl(sv, j + 3);
                float m0 = __shfl(nv, j),     m1 = __shfl(nv, j + 1);
                float m2 = __shfl(nv, j + 2), m3 = __shfl(nv, j + 3);
                float p0 = b2f(h_in[(size_t)s0 * 64 + lane]);
                float p1 = b2f(h_in[(size_t)s1 * 64 + lane]);
                float p2 = b2f(h_in[(size_t)s2 * 64 + lane]);
                float p3 = b2f(h_in[(size_t)s3 * 64 + lane]);
                g += m0 * p0 + m1 * p1 + m2 * p2 + m3 * p3;
            }
            for (; j < cc; j++) {
                int s0 = __shfl(sv, j);
                float m0 = __shfl(nv, j);
                g += m0 * b2f(h_in[(size_t)s0 * 64 + lane]);
            }
        }
        const float s = lds_gemm64(sb[slot], lane, g, wr, bb);
        const float h = tanhf(s);
        const size_t ai = (size_t)n * 64 + lane;
        if (store_h) h_out[ai] = __float2bfloat16(h);
        acc[ai] = (first ? 0.f : acc[ai]) + fc * h;
    }
}

// ---------------- pooling gather (R7-proven) ----------------
__global__ void pool_gather_kernel(const int* __restrict__ base, const int* __restrict__ cnt,
                                   const int* __restrict__ jp, const float* __restrict__ accc,
                                   float* __restrict__ fin, int nn)
{
    const int lane = threadIdx.x & 63;
    const int n = blockIdx.x * (blockDim.x >> 6) + (threadIdx.x >> 6);
    if (n >= nn) return;
    const int m = cnt[n];
    if (m == 0) return;
    const int bs = base[n];
    float s = 0.f;
    for (int t = bs; t < bs + m; t++) {
        int j = jp[t];
        s += accc[(size_t)j * 64 + lane];
    }
    fin[(size_t)n * 64 + lane] += s / (float)m;
}

// ---------------- Decoder (fp32 out, 4-way ILP) ----------------
__global__ void dec_kernel(const float* __restrict__ fin,
                           const float* __restrict__ W1, const float* __restrict__ b1,
                           const float* __restrict__ W2, const float* __restrict__ b2,
                           const float* __restrict__ pa, float* __restrict__ out, int nn)
{
    const int lane = threadIdx.x & 63;
    const int wid  = blockIdx.x * (blockDim.x >> 6) + (threadIdx.x >> 6);
    const int nw   = gridDim.x * (blockDim.x >> 6);
    float w1r[64];
#pragma unroll
    for (int k = 0; k < 64; k++) w1r[k] = W1[k * 64 + lane];
    const float bb1 = b1[lane];
    const float w20 = W2[lane * 2 + 0];
    const float w21 = W2[lane * 2 + 1];
    const float bb20 = b2[0];
    const float bb21 = b2[1];
    const float a = pa[0];
    for (int n = wid; n < nn; n += nw) {
        const float4* fr = (const float4*)(fin + (size_t)n * 64);
        float a0 = bb1, a1 = 0.f, a2 = 0.f, a3 = 0.f;
#pragma unroll
        for (int q = 0; q < 16; q += 4) {
            float4 v0 = fr[q + 0], v1 = fr[q + 1], v2 = fr[q + 2], v3 = fr[q + 3];
            a0 += v0.x * w1r[4*q + 0]  + v0.y * w1r[4*q + 1]  + v0.z * w1r[4*q + 2]  + v0.w * w1r[4*q + 3];
            a1 += v1.x * w1r[4*q + 4]  + v1.y * w1r[4*q + 5]  + v1.z * w1r[4*q + 6]  + v1.w * w1r[4*q + 7];
            a2 += v2.x * w1r[4*q + 8]  + v2.y * w1r[4*q + 9]  + v2.z * w1r[4*q + 10] + v2.w * w1r[4*q + 11];
            a3 += v3.x * w1r[4*q + 12] + v3.y * w1r[4*q + 13] + v3.z * w1r[4*q + 14] + v3.w * w1r[4*q + 15];
        }
        float y = (a0 + a1) + (a2 + a3);
        y = y > 0.f ? y : a * y;
        float p0 = y * w20, p1 = y * w21;
#pragma unroll
        for (int m = 32; m; m >>= 1) { p0 += __shfl_xor(p0, m); p1 += __shfl_xor(p1, m); }
        if (lane == 0) {
            float o0 = p0 + bb20; o0 = o0 > 0.f ? o0 : a * o0;
            float o1 = p1 + bb21; o1 = o1 > 0.f ? o1 : a * o1;
            ((float2*)out)[n] = make_float2(o0, o1);
        }
    }
}

extern "C" void kernel_launch(void* const* d_in, const int* in_sizes, int n_in,
                              void* d_out, int out_size, void* d_ws, size_t ws_size,
                              hipStream_t stream)
{
    const float* stat = (const float*)d_in[0];
    const float* dyn  = (const float*)d_in[1];
    const int*   ei[3]   = {(const int*)d_in[2], (const int*)d_in[4], (const int*)d_in[6]};
    const float* ea[3]   = {(const float*)d_in[3], (const float*)d_in[5], (const float*)d_in[7]};
    const int*   pidx[2] = {(const int*)d_in[8], (const int*)d_in[9]};
    const float* encW1 = (const float*)d_in[10]; const float* encb1 = (const float*)d_in[11];
    const float* encW2 = (const float*)d_in[12]; const float* encb2 = (const float*)d_in[13];
    const float* encpa = (const float*)d_in[14];
    const float* gW    = (const float*)d_in[15]; const float* gbias = (const float*)d_in[16];
    const float* filt  = (const float*)d_in[17];
    const float* dW1   = (const float*)d_in[18]; const float* db1   = (const float*)d_in[19];
    const float* dW2   = (const float*)d_in[20]; const float* db2   = (const float*)d_in[21];
    const float* dpa   = (const float*)d_in[22];

    auto al = [](size_t x) { return (x + 255) & ~(size_t)255; };
    char* w = (char*)d_ws;
    size_t off = 0;
    bf16* X    = (bf16*)(w + off); off += al((size_t)cNTOT * 64 * 2);   // 67.2 MB (h ping)
    bf16* HB   = (bf16*)(w + off); off += al((size_t)cN0 * 64 * 2);     // 51.2 MB (h pong)
    float* FIN = (float*)(w + off); off += al((size_t)cN0 * 64 * 4);    // 102.4 MB
    float* ACCC= (float*)(w + off); off += al((size_t)cN1 * 64 * 4);    // 25.6 MB
    float* DINV= (float*)(w + off); off += al((size_t)cN0 * 4);
    int* CNTI  = (int*)(w + off);  off += al((size_t)cN0 * 4);
    int* BASE  = (int*)(w + off);  off += al((size_t)cN0 * 4);
    int* CUR   = (int*)(w + off);  off += al((size_t)cN0 * 4);
    int* SRCP  = (int*)(w + off);  off += al((size_t)cE0 * 4);
    bf16* NORMP= (bf16*)(w + off); off += al((size_t)cE0 * 2);
    int* JP    = (int*)(w + off);  off += al((size_t)cN1 * 4);
    int* GC    = (int*)(w + off);  off += 256;   // ~263 MB total (proven fit)

    const int Ns[3]  = {cN0, cN1, cN2};
    const int Es[3]  = {cE0, cE1, cE2};
    const int ptr[3] = {0, cN0, cN0 + cN1};
#define NB(x) (((x) + 255) / 256)

    enc_kernel<<<4096, 256, 0, stream>>>(stat, dyn, encW1, encb1, encW2, encb2, encpa, X, cNTOT);

    for (int i = 0; i < 3; i++) {
        const int* srcp_in = ei[i];
        const int* dstp    = ei[i] + Es[i];
        fill1_kernel <<<NB(Ns[i]), 256, 0, stream>>>(DINV, Ns[i]);
        degacc_kernel<<<NB(Es[i]), 256, 0, stream>>>(dstp, ea[i], DINV, Es[i]);
        rsqrt_kernel <<<NB(Ns[i]), 256, 0, stream>>>(DINV, Ns[i]);
        zint_kernel    <<<NB(Ns[i]), 256, 0, stream>>>(CNTI, Ns[i]);
        zint_kernel    <<<1, 256, 0, stream>>>(GC, 1);
        cnt_edge_kernel<<<NB(Es[i]), 256, 0, stream>>>(dstp, CNTI, Es[i]);
        grab_kernel    <<<NB(Ns[i]), 256, 0, stream>>>(CNTI, BASE, CUR, GC, Ns[i]);
        fill_edge_kernel<<<NB(Es[i]), 256, 0, stream>>>(srcp_in, dstp, ea[i], DINV, CUR, SRCP, NORMP, Es[i]);

        bf16* ping = X + (size_t)ptr[i] * 64;
        bf16* pong = HB;
        float* acc_i = (i == 0) ? FIN : ACCC;
        for (int k = 0; k < 3; k++) {
            bf16* hin  = (k & 1) ? pong : ping;
            bf16* hout = (k & 1) ? ping : pong;
            fused_conv_kernel<<<4096, 256, 0, stream>>>(BASE, CNTI, SRCP, NORMP,
                hin, hout, DINV, gW, i * 4096, gbias, i * 64,
                filt, i * 3 + k, (k == 0) ? 1 : 0, (k < 2) ? 1 : 0, acc_i, Ns[i]);
        }
        if (i >= 1) {
            int nj = (i == 1) ? cN1 : cN2;
            const int* pp = pidx[i - 1];
            zint_kernel    <<<NB(cN0), 256, 0, stream>>>(CNTI, cN0);
            zint_kernel    <<<1, 256, 0, stream>>>(GC, 1);
            cnt_idx_kernel <<<NB(nj), 256, 0, stream>>>(pp, CNTI, nj);
            grab_kernel    <<<NB(cN0), 256, 0, stream>>>(CNTI, BASE, CUR, GC, cN0);
            fill_idx_kernel<<<NB(nj), 256, 0, stream>>>(pp, CUR, JP, nj);
            pool_gather_kernel<<<(cN0 + 3) / 4, 256, 0, stream>>>(BASE, CNTI, JP, ACCC, FIN, cN0);
        }
    }
    dec_kernel<<<4096, 256, 0, stream>>>(FIN, dW1, db1, dW2, db2, dpa, (float*)d_out, cN0);
#undef NB
}

// Round 9
// 2271.713 us; speedup vs baseline: 1.5763x; 1.0063x over previous
//
#include <hip/hip_runtime.h>
#include <hip/hip_bf16.h>

typedef __hip_bfloat16 bf16;

// Inputs fp32, output fp32 (established R4/R7). Intermediates bf16, accumulators fp32.
constexpr int cN0 = 400000, cN1 = 100000, cN2 = 25000;
constexpr int cNTOT = cN0 + cN1 + cN2;
constexpr int cE0 = 1600000, cE1 = 400000, cE2 = 100000;

static __device__ __forceinline__ float b2f(bf16 x) { return __bfloat162float(x); }

// LDS-broadcast 64-wide GEMM: lane-value g -> s = bias + sum_k g_k * wr[k]
// Per-wave slot; same-wave DS ordering guarantees write-before-read; wave_barrier
// stops compiler reordering. 1 ds_write + 16 ds_read_b128 (broadcast, conflict-free),
// 4 independent accumulators to break the FMA dependency chain.
static __device__ __forceinline__ float lds_gemm64(float* sb, int lane, float g,
                                                   const float* wr, float bias)
{
    sb[lane] = g;
    __builtin_amdgcn_wave_barrier();
    const float4* sb4 = (const float4*)sb;
    float a0 = bias, a1 = 0.f, a2 = 0.f, a3 = 0.f;
#pragma unroll
    for (int q = 0; q < 16; q += 4) {
        float4 v0 = sb4[q + 0], v1 = sb4[q + 1], v2 = sb4[q + 2], v3 = sb4[q + 3];
        a0 += v0.x * wr[4*q + 0]  + v0.y * wr[4*q + 1]  + v0.z * wr[4*q + 2]  + v0.w * wr[4*q + 3];
        a1 += v1.x * wr[4*q + 4]  + v1.y * wr[4*q + 5]  + v1.z * wr[4*q + 6]  + v1.w * wr[4*q + 7];
        a2 += v2.x * wr[4*q + 8]  + v2.y * wr[4*q + 9]  + v2.z * wr[4*q + 10] + v2.w * wr[4*q + 11];
        a3 += v3.x * wr[4*q + 12] + v3.y * wr[4*q + 13] + v3.z * wr[4*q + 14] + v3.w * wr[4*q + 15];
    }
    __builtin_amdgcn_wave_barrier();   // keep next iteration's write after these reads
    return (a0 + a1) + (a2 + a3);
}

// ---------------- Encoder ----------------
// __launch_bounds__(256,2): 256-VGPR budget so w1r/w2r stay register-resident
// (default occupancy target forced per-node global reloads of W — R8 VGPR=52/64 evidence).
__global__ __launch_bounds__(256, 2)
void enc_kernel(const float* __restrict__ stat, const float* __restrict__ dyn,
                const float* __restrict__ W1, const float* __restrict__ b1,
                const float* __restrict__ W2, const float* __restrict__ b2,
                const float* __restrict__ pa, bf16* __restrict__ X, int nn)
{
    __shared__ float sb[4][64];
    const int lane = threadIdx.x & 63;
    const int slot = threadIdx.x >> 6;
    const int wid  = blockIdx.x * (blockDim.x >> 6) + slot;
    const int nw   = gridDim.x * (blockDim.x >> 6);
    float w1r[16], w2r[64];
#pragma unroll
    for (int k = 0; k < 16; k++) w1r[k] = W1[k * 64 + lane];
#pragma unroll
    for (int k = 0; k < 64; k++) w2r[k] = W2[k * 64 + lane];
    const float bb1 = b1[lane];
    const float bb2 = b2[lane];
    const float a   = pa[0];
    for (int n = wid; n < nn; n += nw) {
        float t1a = bb1, t1b = 0.f;
#pragma unroll
        for (int k = 0; k < 6; k += 2) {
            t1a += stat[(size_t)n * 6 + k]     * w1r[k];
            t1b += stat[(size_t)n * 6 + k + 1] * w1r[k + 1];
        }
#pragma unroll
        for (int k = 0; k < 10; k += 2) {
            t1a += dyn[(size_t)n * 10 + k]     * w1r[6 + k];
            t1b += dyn[(size_t)n * 10 + k + 1] * w1r[7 + k];
        }
        float t1 = t1a + t1b;
        t1 = t1 > 0.f ? t1 : a * t1;
        float t2 = lds_gemm64(sb[slot], lane, t1, w2r, bb2);
        t2 = t2 > 0.f ? t2 : a * t2;
        X[(size_t)n * 64 + lane] = __float2bfloat16(t2);
    }
}

// ---------------- degree / CSR build (R7-proven, unchanged) ----------------
__global__ void zint_kernel(int* p, int n)   { int t = blockIdx.x * 256 + threadIdx.x; if (t < n) p[t] = 0; }
__global__ void fill1_kernel(float* p, int n){ int t = blockIdx.x * 256 + threadIdx.x; if (t < n) p[t] = 1.f; }
__global__ void degacc_kernel(const int* __restrict__ dst, const float* __restrict__ ew,
                              float* __restrict__ deg, int ne)
{
    int e = blockIdx.x * 256 + threadIdx.x;
    if (e < ne) unsafeAtomicAdd(&deg[dst[e]], ew[e]);
}
__global__ void rsqrt_kernel(float* p, int n){ int t = blockIdx.x * 256 + threadIdx.x; if (t < n) p[t] = rsqrtf(p[t]); }
__global__ void cnt_edge_kernel(const int* __restrict__ dst, int* __restrict__ cnt, int ne)
{
    int e = blockIdx.x * 256 + threadIdx.x;
    if (e < ne) atomicAdd(&cnt[dst[e]], 1);
}
__global__ void grab_kernel(const int* __restrict__ cnt, int* __restrict__ base,
                            int* __restrict__ cur, int* __restrict__ gc, int n)
{
    int t = blockIdx.x * 256 + threadIdx.x;
    if (t < n) { int b = atomicAdd(gc, cnt[t]); base[t] = b; cur[t] = b; }
}
__global__ void fill_edge_kernel(const int* __restrict__ src, const int* __restrict__ dst,
                                 const float* __restrict__ ew, const float* __restrict__ dinv,
                                 int* __restrict__ cur, int* __restrict__ srcp,
                                 bf16* __restrict__ normp, int ne)
{
    int e = blockIdx.x * 256 + threadIdx.x;
    if (e >= ne) return;
    int d = dst[e], s = src[e];
    int pos = atomicAdd(&cur[d], 1);
    srcp[pos]  = s;
    normp[pos] = __float2bfloat16(dinv[s] * ew[e] * dinv[d]);
}
__global__ void cnt_idx_kernel(const int* __restrict__ idx, int* __restrict__ cnt, int n)
{
    int j = blockIdx.x * 256 + threadIdx.x;
    if (j < n) atomicAdd(&cnt[idx[j]], 1);
}
__global__ void fill_idx_kernel(const int* __restrict__ idx, int* __restrict__ cur,
                                int* __restrict__ jp, int n)
{
    int j = blockIdx.x * 256 + threadIdx.x;
    if (j >= n) return;
    int pos = atomicAdd(&cur[idx[j]], 1);
    jp[pos] = j;
}

// ---- Fused conv: batched-ILP gather -> LDS-broadcast GEMM -> tanh -> filter acc ----------
__global__ __launch_bounds__(256, 2)
void fused_conv_kernel(const int* __restrict__ base, const int* __restrict__ cnt,
                       const int* __restrict__ srcp, const bf16* __restrict__ normp,
                       const bf16* __restrict__ h_in, bf16* __restrict__ h_out,
                       const float* __restrict__ dinv,
                       const float* __restrict__ W, int woff,
                       const float* __restrict__ bias, int boff,
                       const float* __restrict__ filt, int foff,
                       int first, int store_h, float* __restrict__ acc, int nn)
{
    __shared__ float sb[4][64];
    const int lane = threadIdx.x & 63;
    const int slot = threadIdx.x >> 6;
    const int wid  = blockIdx.x * (blockDim.x >> 6) + slot;
    const int nw   = gridDim.x * (blockDim.x >> 6);
    float wr[64];
#pragma unroll
    for (int k = 0; k < 64; k++) wr[k] = W[(size_t)woff + k * 64 + lane];
    const float bb = bias[boff + lane];
    const float fc = filt[foff];
    for (int n = wid; n < nn; n += nw) {
        const int bs = base[n], c = cnt[n];
        const float di = dinv[n];
        float g0 = b2f(h_in[(size_t)n * 64 + lane]) * di * di;   // self-loop term
        float g1 = 0.f, g2 = 0.f, g3 = 0.f;                       // independent chains
        for (int ch = 0; ch < c; ch += 64) {
            const int cc = min(64, c - ch);
            int sv = 0; float nv = 0.f;
            if (lane < cc) {                        // one coalesced batch load of (src, norm)
                sv = srcp[bs + ch + lane];
                nv = b2f(normp[bs + ch + lane]);
            }
            int j = 0;
            for (; j + 4 <= cc; j += 4) {           // 4 independent row gathers in flight
                int   s0 = __shfl(sv, j),     s1 = __shfl(sv, j + 1);
                int   s2 = __shfl(sv, j + 2), s3 = __shfl(sv, j + 3);
                float m0 = __shfl(nv, j),     m1 = __shfl(nv, j + 1);
                float m2 = __shfl(nv, j + 2), m3 = __shfl(nv, j + 3);
                float p0 = b2f(h_in[(size_t)s0 * 64 + lane]);
                float p1 = b2f(h_in[(size_t)s1 * 64 + lane]);
                float p2 = b2f(h_in[(size_t)s2 * 64 + lane]);
                float p3 = b2f(h_in[(size_t)s3 * 64 + lane]);
                g0 += m0 * p0; g1 += m1 * p1; g2 += m2 * p2; g3 += m3 * p3;
            }
            for (; j < cc; j++) {
                int s0 = __shfl(sv, j);
                float m0 = __shfl(nv, j);
                g1 += m0 * b2f(h_in[(size_t)s0 * 64 + lane]);
            }
        }
        const float g = (g0 + g1) + (g2 + g3);
        const float s = lds_gemm64(sb[slot], lane, g, wr, bb);
        const float h = tanhf(s);
        const size_t ai = (size_t)n * 64 + lane;
        if (store_h) h_out[ai] = __float2bfloat16(h);
        acc[ai] = (first ? 0.f : acc[ai]) + fc * h;
    }
}

// ---------------- pooling gather (R7-proven) ----------------
__global__ void pool_gather_kernel(const int* __restrict__ base, const int* __restrict__ cnt,
                                   const int* __restrict__ jp, const float* __restrict__ accc,
                                   float* __restrict__ fin, int nn)
{
    const int lane = threadIdx.x & 63;
    const int n = blockIdx.x * (blockDim.x >> 6) + (threadIdx.x >> 6);
    if (n >= nn) return;
    const int m = cnt[n];
    if (m == 0) return;
    const int bs = base[n];
    float s = 0.f;
    for (int t = bs; t < bs + m; t++) {
        int j = jp[t];
        s += accc[(size_t)j * 64 + lane];
    }
    fin[(size_t)n * 64 + lane] += s / (float)m;
}

// ---------------- Decoder (fp32 out, 4-way ILP) ----------------
__global__ __launch_bounds__(256, 2)
void dec_kernel(const float* __restrict__ fin,
                const float* __restrict__ W1, const float* __restrict__ b1,
                const float* __restrict__ W2, const float* __restrict__ b2,
                const float* __restrict__ pa, float* __restrict__ out, int nn)
{
    const int lane = threadIdx.x & 63;
    const int wid  = blockIdx.x * (blockDim.x >> 6) + (threadIdx.x >> 6);
    const int nw   = gridDim.x * (blockDim.x >> 6);
    float w1r[64];
#pragma unroll
    for (int k = 0; k < 64; k++) w1r[k] = W1[k * 64 + lane];
    const float bb1 = b1[lane];
    const float w20 = W2[lane * 2 + 0];
    const float w21 = W2[lane * 2 + 1];
    const float bb20 = b2[0];
    const float bb21 = b2[1];
    const float a = pa[0];
    for (int n = wid; n < nn; n += nw) {
        const float4* fr = (const float4*)(fin + (size_t)n * 64);
        float a0 = bb1, a1 = 0.f, a2 = 0.f, a3 = 0.f;
#pragma unroll
        for (int q = 0; q < 16; q += 4) {
            float4 v0 = fr[q + 0], v1 = fr[q + 1], v2 = fr[q + 2], v3 = fr[q + 3];
            a0 += v0.x * w1r[4*q + 0]  + v0.y * w1r[4*q + 1]  + v0.z * w1r[4*q + 2]  + v0.w * w1r[4*q + 3];
            a1 += v1.x * w1r[4*q + 4]  + v1.y * w1r[4*q + 5]  + v1.z * w1r[4*q + 6]  + v1.w * w1r[4*q + 7];
            a2 += v2.x * w1r[4*q + 8]  + v2.y * w1r[4*q + 9]  + v2.z * w1r[4*q + 10] + v2.w * w1r[4*q + 11];
            a3 += v3.x * w1r[4*q + 12] + v3.y * w1r[4*q + 13] + v3.z * w1r[4*q + 14] + v3.w * w1r[4*q + 15];
        }
        float y = (a0 + a1) + (a2 + a3);
        y = y > 0.f ? y : a * y;
        float p0 = y * w20, p1 = y * w21;
#pragma unroll
        for (int m = 32; m; m >>= 1) { p0 += __shfl_xor(p0, m); p1 += __shfl_xor(p1, m); }
        if (lane == 0) {
            float o0 = p0 + bb20; o0 = o0 > 0.f ? o0 : a * o0;
            float o1 = p1 + bb21; o1 = o1 > 0.f ? o1 : a * o1;
            ((float2*)out)[n] = make_float2(o0, o1);
        }
    }
}

extern "C" void kernel_launch(void* const* d_in, const int* in_sizes, int n_in,
                              void* d_out, int out_size, void* d_ws, size_t ws_size,
                              hipStream_t stream)
{
    const float* stat = (const float*)d_in[0];
    const float* dyn  = (const float*)d_in[1];
    const int*   ei[3]   = {(const int*)d_in[2], (const int*)d_in[4], (const int*)d_in[6]};
    const float* ea[3]   = {(const float*)d_in[3], (const float*)d_in[5], (const float*)d_in[7]};
    const int*   pidx[2] = {(const int*)d_in[8], (const int*)d_in[9]};
    const float* encW1 = (const float*)d_in[10]; const float* encb1 = (const float*)d_in[11];
    const float* encW2 = (const float*)d_in[12]; const float* encb2 = (const float*)d_in[13];
    const float* encpa = (const float*)d_in[14];
    const float* gW    = (const float*)d_in[15]; const float* gbias = (const float*)d_in[16];
    const float* filt  = (const float*)d_in[17];
    const float* dW1   = (const float*)d_in[18]; const float* db1   = (const float*)d_in[19];
    const float* dW2   = (const float*)d_in[20]; const float* db2   = (const float*)d_in[21];
    const float* dpa   = (const float*)d_in[22];

    auto al = [](size_t x) { return (x + 255) & ~(size_t)255; };
    char* w = (char*)d_ws;
    size_t off = 0;
    bf16* X    = (bf16*)(w + off); off += al((size_t)cNTOT * 64 * 2);   // 67.2 MB (h ping)
    bf16* HB   = (bf16*)(w + off); off += al((size_t)cN0 * 64 * 2);     // 51.2 MB (h pong)
    float* FIN = (float*)(w + off); off += al((size_t)cN0 * 64 * 4);    // 102.4 MB
    float* ACCC= (float*)(w + off); off += al((size_t)cN1 * 64 * 4);    // 25.6 MB
    float* DINV= (float*)(w + off); off += al((size_t)cN0 * 4);
    int* CNTI  = (int*)(w + off);  off += al((size_t)cN0 * 4);
    int* BASE  = (int*)(w + off);  off += al((size_t)cN0 * 4);
    int* CUR   = (int*)(w + off);  off += al((size_t)cN0 * 4);
    int* SRCP  = (int*)(w + off);  off += al((size_t)cE0 * 4);
    bf16* NORMP= (bf16*)(w + off); off += al((size_t)cE0 * 2);
    int* JP    = (int*)(w + off);  off += al((size_t)cN1 * 4);
    int* GC    = (int*)(w + off);  off += 256;   // ~263 MB total (proven fit)

    const int Ns[3]  = {cN0, cN1, cN2};
    const int Es[3]  = {cE0, cE1, cE2};
    const int ptr[3] = {0, cN0, cN0 + cN1};
#define NB(x) (((x) + 255) / 256)

    enc_kernel<<<4096, 256, 0, stream>>>(stat, dyn, encW1, encb1, encW2, encb2, encpa, X, cNTOT);

    for (int i = 0; i < 3; i++) {
        const int* srcp_in = ei[i];
        const int* dstp    = ei[i] + Es[i];
        fill1_kernel <<<NB(Ns[i]), 256, 0, stream>>>(DINV, Ns[i]);
        degacc_kernel<<<NB(Es[i]), 256, 0, stream>>>(dstp, ea[i], DINV, Es[i]);
        rsqrt_kernel <<<NB(Ns[i]), 256, 0, stream>>>(DINV, Ns[i]);
        zint_kernel    <<<NB(Ns[i]), 256, 0, stream>>>(CNTI, Ns[i]);
        zint_kernel    <<<1, 256, 0, stream>>>(GC, 1);
        cnt_edge_kernel<<<NB(Es[i]), 256, 0, stream>>>(dstp, CNTI, Es[i]);
        grab_kernel    <<<NB(Ns[i]), 256, 0, stream>>>(CNTI, BASE, CUR, GC, Ns[i]);
        fill_edge_kernel<<<NB(Es[i]), 256, 0, stream>>>(srcp_in, dstp, ea[i], DINV, CUR, SRCP, NORMP, Es[i]);

        bf16* ping = X + (size_t)ptr[i] * 64;
        bf16* pong = HB;
        float* acc_i = (i == 0) ? FIN : ACCC;
        for (int k = 0; k < 3; k++) {
            bf16* hin  = (k & 1) ? pong : ping;
            bf16* hout = (k & 1) ? ping : pong;
            fused_conv_kernel<<<4096, 256, 0, stream>>>(BASE, CNTI, SRCP, NORMP,
                hin, hout, DINV, gW, i * 4096, gbias, i * 64,
                filt, i * 3 + k, (k == 0) ? 1 : 0, (k < 2) ? 1 : 0, acc_i, Ns[i]);
        }
        if (i >= 1) {
            int nj = (i == 1) ? cN1 : cN2;
            const int* pp = pidx[i - 1];
            zint_kernel    <<<NB(cN0), 256, 0, stream>>>(CNTI, cN0);
            zint_kernel    <<<1, 256, 0, stream>>>(GC, 1);
            cnt_idx_kernel <<<NB(nj), 256, 0, stream>>>(pp, CNTI, nj);
            grab_kernel    <<<NB(cN0), 256, 0, stream>>>(CNTI, BASE, CUR, GC, cN0);
            fill_idx_kernel<<<NB(nj), 256, 0, stream>>>(pp, CUR, JP, nj);
            pool_gather_kernel<<<(cN0 + 3) / 4, 256, 0, stream>>>(BASE, CNTI, JP, ACCC, FIN, cN0);
        }
    }
    dec_kernel<<<4096, 256, 0, stream>>>(FIN, dW1, db1, dW2, db2, dpa, (float*)d_out, cN0);
#undef NB
}